// Round 11
// baseline (527.125 us; speedup 1.0000x reference)
//
#include <hip/hip_runtime.h>
#include <math.h>

#define NPTS 4096
#define LOGN 8.317766166719343f   // log(4096)
#define LN2f 0.6931471805599453f
#define LOG2E 1.4426950408889634f

#define NSTEPS 11
#define JSPLIT 2
#define JCHUNK (NPTS / JSPLIT)            // 2048 columns per block
#define RPW 8                             // rows per wave
#define RPB 32                            // rows per block (4 waves)
#define NRBLK (NPTS / RPB)                // 128
#define BPP (NRBLK * JSPLIT)              // 256 blocks per problem; grid = 768

typedef float f2 __attribute__((ext_vector_type(2)));
static __device__ __forceinline__ f2 mk2(float a, float b) { f2 r; r.x = a; r.y = b; return r; }

// ws float layout (R4 champion):
// SoA points: PT(cloud, coord): cloud 0=x,1=y; coord 0=x,1=y,2=z,3=|p|^2
// m_part @ MPART_OFF: [(prob*2+side)*JSPLIT + p][row]   (side 0=f, 1=g)
// s_part @ SPART_OFF: same layout
// probe scratch @ float offset 262144 (1 MB) — diagnostics only
#define PT(cloud, coord) ((cloud) * 4 * NPTS + (coord) * NPTS)
#define MPART_OFF (8 * NPTS)
#define SPART_OFF (MPART_OFF + 6 * JSPLIT * NPTS)
#define PROBE_OFF 262144

__global__ void prep_kernel(const float* __restrict__ x, const float* __restrict__ y,
                            float* __restrict__ ws) {
    int j = blockIdx.x * 256 + threadIdx.x;
    if (j >= NPTS) return;
    float ax = x[3*j], ay = x[3*j+1], az = x[3*j+2];
    ws[PT(0,0)+j] = ax; ws[PT(0,1)+j] = ay; ws[PT(0,2)+j] = az;
    ws[PT(0,3)+j] = ax*ax + ay*ay + az*az;
    float bx = y[3*j], by = y[3*j+1], bz = y[3*j+2];
    ws[PT(1,0)+j] = bx; ws[PT(1,1)+j] = by; ws[PT(1,2)+j] = bz;
    ws[PT(1,3)+j] = bx*bx + by*by + bz*bz;
    // init partials so decoded dual == 0 at any eps: lse2 = 12 = log2(4096)
    float* mp = ws + MPART_OFF;
    float* sp = ws + SPART_OFF;
    #pragma unroll
    for (int ps = 0; ps < 6; ++ps) {
        mp[(ps*JSPLIT+0)*NPTS + j] = 12.0f; sp[(ps*JSPLIT+0)*NPTS + j] = 1.0f;
        mp[(ps*JSPLIT+1)*NPTS + j] = 0.0f;  sp[(ps*JSPLIT+1)*NPTS + j] = 0.0f;
    }
}

// One Sinkhorn half-update, online chunked-max LSE (R4 champion, verbatim).
__launch_bounds__(256, 3)
__global__ void sinkhorn_step(float* __restrict__ ws, float eps, float eps_dec, int half) {
    int bid = blockIdx.x;
    int prob = bid / BPP;                 // 0: xy, 1: xx, 2: yy
    int rem  = bid % BPP;
    int js   = rem & (JSPLIT - 1);
    int rblk = rem / JSPLIT;

    int rc, cc, in_side, out_side;
    if (half == 0) { rc = (prob == 2) ? 1 : 0; cc = (prob == 1) ? 0 : 1; in_side = 1; out_side = 0; }
    else           { rc = (prob == 1) ? 0 : 1; cc = (prob == 2) ? 1 : 0; in_side = 0; out_side = 1; }

    const float k = LOG2E / eps;          // base-2 log scale
    const float nhk = -0.5f * k;
    const int jbase = js * JCHUNK;

    __shared__ float bxL[JCHUNK], byL[JCHUNK], bzL[JCHUNK], uL[JCHUNK];  // 32 KB

    // ---- stage SoA cols + decode input duals into u = k*(g_j - 0.5*|b_j|^2) ----
    {
        const float* cx = ws + PT(cc, 0);
        const float* cy = ws + PT(cc, 1);
        const float* cz = ws + PT(cc, 2);
        const float* cw = ws + PT(cc, 3);
        const float* mp = ws + MPART_OFF + (prob*2 + in_side) * JSPLIT * NPTS;
        const float* sp = ws + SPART_OFF + (prob*2 + in_side) * JSPLIT * NPTS;
        for (int i = threadIdx.x; i < JCHUNK; i += 256) {
            int j = jbase + i;
            float m0 = mp[j], m1 = mp[NPTS + j];
            float s0 = sp[j], s1 = sp[NPTS + j];
            float M = fmaxf(m0, m1);
            float ssum = fmaf(s0, __builtin_amdgcn_exp2f(m0 - M),
                              s1 * __builtin_amdgcn_exp2f(m1 - M));
            float lse2 = M + __builtin_amdgcn_logf(ssum);
            float g = -eps_dec * fmaf(LN2f, lse2, -LOGN);
            bxL[i] = cx[j]; byL[i] = cy[j]; bzL[i] = cz[j];
            uL[i] = fmaf(cw[j], nhk, g * k);
        }
    }
    __syncthreads();

    int wave = threadIdx.x >> 6;
    int lane = threadIdx.x & 63;
    int r0 = rblk * RPB + wave * RPW;

    const float* rx = ws + PT(rc, 0);
    const float* ry = ws + PT(rc, 1);
    const float* rz = ws + PT(rc, 2);
    const float* rw = ws + PT(rc, 3);

    f2 AX[RPW], AY[RPW], AZ[RPW];
    float rak[RPW], m[RPW], s[RPW];
    #pragma unroll
    for (int r = 0; r < RPW; ++r) {
        float ax = rx[r0+r] * k, ay = ry[r0+r] * k, az = rz[r0+r] * k;
        AX[r] = mk2(ax, ax); AY[r] = mk2(ay, ay); AZ[r] = mk2(az, az);
        rak[r] = nhk * rw[r0+r];
        m[r] = -INFINITY; s[r] = 0.0f;
    }

    // ---- main loop: 8 j's per lane per superiter, chunk-local max, 1 rescale ----
    for (int su = 0; su < JCHUNK / 512; ++su) {     // 4 superiters
        int c0 = su * 512 + lane;
        f2 BX[4], BY[4], BZ[4], U[4];
        #pragma unroll
        for (int p = 0; p < 4; ++p) {
            int j0 = c0 + p * 128;
            BX[p] = mk2(bxL[j0], bxL[j0 + 64]);
            BY[p] = mk2(byL[j0], byL[j0 + 64]);
            BZ[p] = mk2(bzL[j0], bzL[j0 + 64]);
            U[p]  = mk2(uL[j0],  uL[j0 + 64]);
        }
        #pragma unroll
        for (int r = 0; r < RPW; ++r) {
            f2 t0 = __builtin_elementwise_fma(AX[r], BX[0],
                     __builtin_elementwise_fma(AY[r], BY[0],
                      __builtin_elementwise_fma(AZ[r], BZ[0], U[0])));
            f2 t1 = __builtin_elementwise_fma(AX[r], BX[1],
                     __builtin_elementwise_fma(AY[r], BY[1],
                      __builtin_elementwise_fma(AZ[r], BZ[1], U[1])));
            f2 t2 = __builtin_elementwise_fma(AX[r], BX[2],
                     __builtin_elementwise_fma(AY[r], BY[2],
                      __builtin_elementwise_fma(AZ[r], BZ[2], U[2])));
            f2 t3 = __builtin_elementwise_fma(AX[r], BX[3],
                     __builtin_elementwise_fma(AY[r], BY[3],
                      __builtin_elementwise_fma(AZ[r], BZ[3], U[3])));
            f2 q = __builtin_elementwise_max(
                     __builtin_elementwise_max(t0, t1),
                     __builtin_elementwise_max(t2, t3));
            float mn = fmaxf(fmaxf(q.x, q.y), m[r]);       // v_max3
            float er = __builtin_amdgcn_exp2f(m[r] - mn);  // chunk rescale (1/8 per elem)
            f2 mn2 = mk2(mn, mn);
            f2 d0 = t0 - mn2, d1 = t1 - mn2, d2 = t2 - mn2, d3 = t3 - mn2;
            f2 e0, e1, e2, e3;
            e0.x = __builtin_amdgcn_exp2f(d0.x); e0.y = __builtin_amdgcn_exp2f(d0.y);
            e1.x = __builtin_amdgcn_exp2f(d1.x); e1.y = __builtin_amdgcn_exp2f(d1.y);
            e2.x = __builtin_amdgcn_exp2f(d2.x); e2.y = __builtin_amdgcn_exp2f(d2.y);
            e3.x = __builtin_amdgcn_exp2f(d3.x); e3.y = __builtin_amdgcn_exp2f(d3.y);
            f2 acc = (e0 + e1) + (e2 + e3);
            s[r] = fmaf(s[r], er, acc.x + acc.y);
            m[r] = mn;
        }
    }

    // ---- wave reduce: max butterfly, one rescale, sum butterfly; write partial ----
    float* mout = ws + MPART_OFF + ((prob*2 + out_side) * JSPLIT + js) * NPTS + r0;
    float* sout = ws + SPART_OFF + ((prob*2 + out_side) * JSPLIT + js) * NPTS + r0;
    #pragma unroll
    for (int r = 0; r < RPW; ++r) {
        float M = m[r];
        for (int off = 32; off; off >>= 1) M = fmaxf(M, __shfl_xor(M, off));
        float ss = s[r] * __builtin_amdgcn_exp2f(m[r] - M);
        for (int off = 32; off; off >>= 1) ss += __shfl_xor(ss, off);
        if (lane == 0) { mout[r] = M + rak[r]; sout[r] = ss; }
    }
}

// ---- DIAGNOSTIC PROBE (copy of sinkhorn_step, repeated `reps` times, scratch
// output). NOEXP=1 replaces every exp2 with identity to isolate the trans share.
// All results stay live via the scratch store — no DCE (rule #17).
template <int NOEXP>
__launch_bounds__(256, 3)
__global__ void sinkhorn_probe(float* __restrict__ ws, float eps, int reps) {
    int bid = blockIdx.x;
    int prob = bid / BPP;
    int rem  = bid % BPP;
    int js   = rem & (JSPLIT - 1);
    int rblk = rem / JSPLIT;
    int rc = (prob == 2) ? 1 : 0, cc = (prob == 1) ? 0 : 1, in_side = 1;  // half=0 pattern

    const float k = LOG2E / eps;
    const float nhk = -0.5f * k;
    const int jbase = js * JCHUNK;

    __shared__ float bxL[JCHUNK], byL[JCHUNK], bzL[JCHUNK], uL[JCHUNK];

    for (int rep = 0; rep < reps; ++rep) {
        {
            const float* cx = ws + PT(cc, 0);
            const float* cy = ws + PT(cc, 1);
            const float* cz = ws + PT(cc, 2);
            const float* cw = ws + PT(cc, 3);
            const float* mp = ws + MPART_OFF + (prob*2 + in_side) * JSPLIT * NPTS;
            const float* sp = ws + SPART_OFF + (prob*2 + in_side) * JSPLIT * NPTS;
            for (int i = threadIdx.x; i < JCHUNK; i += 256) {
                int j = jbase + i;
                float m0 = mp[j], m1 = mp[NPTS + j];
                float s0 = sp[j], s1 = sp[NPTS + j];
                float M = fmaxf(m0, m1);
                float ssum = fmaf(s0, __builtin_amdgcn_exp2f(m0 - M),
                                  s1 * __builtin_amdgcn_exp2f(m1 - M));
                float lse2 = M + __builtin_amdgcn_logf(ssum);
                float g = -eps * fmaf(LN2f, lse2, -LOGN);
                bxL[i] = cx[j]; byL[i] = cy[j]; bzL[i] = cz[j];
                uL[i] = fmaf(cw[j], nhk, g * k);
            }
        }
        __syncthreads();

        int wave = threadIdx.x >> 6;
        int lane = threadIdx.x & 63;
        int r0 = rblk * RPB + wave * RPW;
        const float* rx = ws + PT(rc, 0);
        const float* ry = ws + PT(rc, 1);
        const float* rz = ws + PT(rc, 2);
        const float* rw = ws + PT(rc, 3);

        f2 AX[RPW], AY[RPW], AZ[RPW];
        float rak[RPW], m[RPW], s[RPW];
        #pragma unroll
        for (int r = 0; r < RPW; ++r) {
            float ax = rx[r0+r] * k, ay = ry[r0+r] * k, az = rz[r0+r] * k;
            AX[r] = mk2(ax, ax); AY[r] = mk2(ay, ay); AZ[r] = mk2(az, az);
            rak[r] = nhk * rw[r0+r];
            m[r] = -INFINITY; s[r] = 0.0f;
        }

        for (int su = 0; su < JCHUNK / 512; ++su) {
            int c0 = su * 512 + lane;
            f2 BX[4], BY[4], BZ[4], U[4];
            #pragma unroll
            for (int p = 0; p < 4; ++p) {
                int j0 = c0 + p * 128;
                BX[p] = mk2(bxL[j0], bxL[j0 + 64]);
                BY[p] = mk2(byL[j0], byL[j0 + 64]);
                BZ[p] = mk2(bzL[j0], bzL[j0 + 64]);
                U[p]  = mk2(uL[j0],  uL[j0 + 64]);
            }
            #pragma unroll
            for (int r = 0; r < RPW; ++r) {
                f2 t0 = __builtin_elementwise_fma(AX[r], BX[0],
                         __builtin_elementwise_fma(AY[r], BY[0],
                          __builtin_elementwise_fma(AZ[r], BZ[0], U[0])));
                f2 t1 = __builtin_elementwise_fma(AX[r], BX[1],
                         __builtin_elementwise_fma(AY[r], BY[1],
                          __builtin_elementwise_fma(AZ[r], BZ[1], U[1])));
                f2 t2 = __builtin_elementwise_fma(AX[r], BX[2],
                         __builtin_elementwise_fma(AY[r], BY[2],
                          __builtin_elementwise_fma(AZ[r], BZ[2], U[2])));
                f2 t3 = __builtin_elementwise_fma(AX[r], BX[3],
                         __builtin_elementwise_fma(AY[r], BY[3],
                          __builtin_elementwise_fma(AZ[r], BZ[3], U[3])));
                f2 q = __builtin_elementwise_max(
                         __builtin_elementwise_max(t0, t1),
                         __builtin_elementwise_max(t2, t3));
                float mn = fmaxf(fmaxf(q.x, q.y), m[r]);
                float er;
                f2 mn2 = mk2(mn, mn);
                f2 d0 = t0 - mn2, d1 = t1 - mn2, d2 = t2 - mn2, d3 = t3 - mn2;
                f2 e0, e1, e2, e3;
                if constexpr (NOEXP) {
                    er = m[r] - mn;                 // identity stand-ins, same dataflow
                    e0 = d0; e1 = d1; e2 = d2; e3 = d3;
                } else {
                    er = __builtin_amdgcn_exp2f(m[r] - mn);
                    e0.x = __builtin_amdgcn_exp2f(d0.x); e0.y = __builtin_amdgcn_exp2f(d0.y);
                    e1.x = __builtin_amdgcn_exp2f(d1.x); e1.y = __builtin_amdgcn_exp2f(d1.y);
                    e2.x = __builtin_amdgcn_exp2f(d2.x); e2.y = __builtin_amdgcn_exp2f(d2.y);
                    e3.x = __builtin_amdgcn_exp2f(d3.x); e3.y = __builtin_amdgcn_exp2f(d3.y);
                }
                f2 acc = (e0 + e1) + (e2 + e3);
                s[r] = fmaf(s[r], er, acc.x + acc.y);
                m[r] = mn;
            }
        }

        float* mout = ws + PROBE_OFF + (js * NPTS) + r0;
        float* sout = ws + PROBE_OFF + ((2 + js) * NPTS) + r0;
        #pragma unroll
        for (int r = 0; r < RPW; ++r) {
            float M = m[r];
            for (int off = 32; off; off >>= 1) M = fmaxf(M, __shfl_xor(M, off));
            float ss = s[r] * ((NOEXP) ? (m[r] - M) : __builtin_amdgcn_exp2f(m[r] - M));
            for (int off = 32; off; off >>= 1) ss += __shfl_xor(ss, off);
            if (lane == 0) { mout[r] = M + rak[r]; sout[r] = ss; }
        }
        __syncthreads();
    }
}

__global__ void finalize_kernel(const float* __restrict__ ws, float* __restrict__ out,
                                float eps) {
    const float* mp = ws + MPART_OFF;
    const float* sp = ws + SPART_OFF;
    int tid = threadIdx.x;
    double acc = 0.0;
    for (int idx = tid; idx < 6 * NPTS; idx += 256) {
        int ps = idx >> 12;            // prob*2+side
        int row = idx & (NPTS - 1);
        int base = ps * JSPLIT * NPTS + row;
        float m0 = mp[base], m1 = mp[base + NPTS];
        float s0 = sp[base], s1 = sp[base + NPTS];
        float M = fmaxf(m0, m1);
        float ssum = fmaf(s0, __builtin_amdgcn_exp2f(m0 - M),
                          s1 * __builtin_amdgcn_exp2f(m1 - M));
        float lse2 = M + __builtin_amdgcn_logf(ssum);
        float dual = -eps * fmaf(LN2f, lse2, -LOGN);
        acc += ((ps < 2) ? 1.0 : -0.5) * (double)dual;
    }
    for (int off = 32; off; off >>= 1) acc += __shfl_xor(acc, off);
    __shared__ double red[4];
    int wave = tid >> 6, lane = tid & 63;
    if (lane == 0) red[wave] = acc;
    __syncthreads();
    if (tid == 0) out[0] = (float)((red[0] + red[1] + red[2] + red[3]) / (double)NPTS);
}

extern "C" void kernel_launch(void* const* d_in, const int* in_sizes, int n_in,
                              void* d_out, int out_size, void* d_ws, size_t ws_size,
                              hipStream_t stream) {
    const float* x = (const float*)d_in[0];
    const float* y = (const float*)d_in[1];
    float* ws = (float*)d_ws;
    float* out = (float*)d_out;

    prep_kernel<<<dim3((NPTS + 255) / 256), dim3(256), 0, stream>>>(x, y, ws);

    float eps_list[NSTEPS];
    for (int st = 0; st < NSTEPS; ++st)
        eps_list[st] = (st < 6) ? ldexpf(4.0f, -2 * st) : 0.0025f;

    for (int st = 0; st < NSTEPS; ++st) {
        float ep = eps_list[st];
        float ed0 = (st == 0) ? ep : eps_list[st - 1];
        sinkhorn_step<<<dim3(3 * BPP), dim3(256), 0, stream>>>(ws, ep, ed0, 0);
        sinkhorn_step<<<dim3(3 * BPP), dim3(256), 0, stream>>>(ws, ep, ep, 1);
    }

    finalize_kernel<<<dim3(1), dim3(256), 0, stream>>>(ws, out, eps_list[NSTEPS - 1]);

    // diagnostics: land the hot loop in the rocprof top-5 (fills are ~39us).
    sinkhorn_probe<0><<<dim3(3 * BPP), dim3(256), 0, stream>>>(ws, eps_list[NSTEPS - 1], 3);
    sinkhorn_probe<1><<<dim3(3 * BPP), dim3(256), 0, stream>>>(ws, eps_list[NSTEPS - 1], 6);
}

// Round 12
// 468.951 us; speedup vs baseline: 1.1240x; 1.1240x over previous
//
#include <hip/hip_runtime.h>
#include <math.h>

#define NPTS 4096
#define LOGN 8.317766166719343f   // log(4096)
#define LN2f 0.6931471805599453f
#define LOG2E 1.4426950408889634f

#define NSTEPS 11
#define JSPLIT 2
#define JCHUNK (NPTS / JSPLIT)            // 2048 columns per block
#define RPW 8                             // rows per wave
#define RPB 32                            // rows per block (4 waves)
#define NRBLK (NPTS / RPB)                // 128
#define BPP (NRBLK * JSPLIT)              // 256 blocks per problem; grid = 768

typedef float f2 __attribute__((ext_vector_type(2)));
static __device__ __forceinline__ f2 mk2(float a, float b) { f2 r; r.x = a; r.y = b; return r; }
static __device__ __forceinline__ float fmax3(float a, float b, float c) {
    return fmaxf(fmaxf(a, b), c);      // fuses to v_max3_f32
}

// ws float layout (R4 champion):
// SoA points: PT(cloud, coord): cloud 0=x,1=y; coord 0=x,1=y,2=z,3=|p|^2
// m_part @ MPART_OFF: [(prob*2+side)*JSPLIT + p][row]   (side 0=f, 1=g)
// s_part @ SPART_OFF: same layout
#define PT(cloud, coord) ((cloud) * 4 * NPTS + (coord) * NPTS)
#define MPART_OFF (8 * NPTS)
#define SPART_OFF (MPART_OFF + 6 * JSPLIT * NPTS)

__global__ void prep_kernel(const float* __restrict__ x, const float* __restrict__ y,
                            float* __restrict__ ws) {
    int j = blockIdx.x * 256 + threadIdx.x;
    if (j >= NPTS) return;
    float ax = x[3*j], ay = x[3*j+1], az = x[3*j+2];
    ws[PT(0,0)+j] = ax; ws[PT(0,1)+j] = ay; ws[PT(0,2)+j] = az;
    ws[PT(0,3)+j] = ax*ax + ay*ay + az*az;
    float bx = y[3*j], by = y[3*j+1], bz = y[3*j+2];
    ws[PT(1,0)+j] = bx; ws[PT(1,1)+j] = by; ws[PT(1,2)+j] = bz;
    ws[PT(1,3)+j] = bx*bx + by*by + bz*bz;
    // init partials so decoded dual == 0 at any eps: lse2 = 12 = log2(4096)
    float* mp = ws + MPART_OFF;
    float* sp = ws + SPART_OFF;
    #pragma unroll
    for (int ps = 0; ps < 6; ++ps) {
        mp[(ps*JSPLIT+0)*NPTS + j] = 12.0f; sp[(ps*JSPLIT+0)*NPTS + j] = 1.0f;
        mp[(ps*JSPLIT+1)*NPTS + j] = 0.0f;  sp[(ps*JSPLIT+1)*NPTS + j] = 0.0f;
    }
}

// ---- helpers for the software-pipelined main loop (all static indexing) ----
static __device__ __forceinline__ void load_su(const float* __restrict__ bxL,
        const float* __restrict__ byL, const float* __restrict__ bzL,
        const float* __restrict__ uL, int c0,
        f2 BX[4], f2 BY[4], f2 BZ[4], f2 U[4]) {
    #pragma unroll
    for (int p = 0; p < 4; ++p) {
        int j0 = c0 + p * 128;
        BX[p] = mk2(bxL[j0], bxL[j0 + 64]);
        BY[p] = mk2(byL[j0], byL[j0 + 64]);
        BZ[p] = mk2(bzL[j0], bzL[j0 + 64]);
        U[p]  = mk2(uL[j0],  uL[j0 + 64]);
    }
}

static __device__ __forceinline__ void compute_su(const f2 BX[4], const f2 BY[4],
        const f2 BZ[4], const f2 U[4], const f2 AX[RPW], const f2 AY[RPW],
        const f2 AZ[RPW], float m[RPW], float s[RPW]) {
    #pragma unroll
    for (int r = 0; r < RPW; ++r) {
        f2 t0 = __builtin_elementwise_fma(AX[r], BX[0],
                 __builtin_elementwise_fma(AY[r], BY[0],
                  __builtin_elementwise_fma(AZ[r], BZ[0], U[0])));
        f2 t1 = __builtin_elementwise_fma(AX[r], BX[1],
                 __builtin_elementwise_fma(AY[r], BY[1],
                  __builtin_elementwise_fma(AZ[r], BZ[1], U[1])));
        f2 t2 = __builtin_elementwise_fma(AX[r], BX[2],
                 __builtin_elementwise_fma(AY[r], BY[2],
                  __builtin_elementwise_fma(AZ[r], BZ[2], U[2])));
        f2 t3 = __builtin_elementwise_fma(AX[r], BX[3],
                 __builtin_elementwise_fma(AY[r], BY[3],
                  __builtin_elementwise_fma(AZ[r], BZ[3], U[3])));
        // chunk max via v_max3 tree (4 instrs)
        float mn = fmax3(fmax3(t0.x, t0.y, t1.x),
                         fmax3(t1.y, t2.x, t2.y),
                         fmax3(t3.x, t3.y, m[r]));
        float er = __builtin_amdgcn_exp2f(m[r] - mn);  // 1 rescale per chunk of 8
        f2 mn2 = mk2(mn, mn);
        f2 d0 = t0 - mn2, d1 = t1 - mn2, d2 = t2 - mn2, d3 = t3 - mn2;
        f2 e0, e1, e2, e3;
        e0.x = __builtin_amdgcn_exp2f(d0.x); e0.y = __builtin_amdgcn_exp2f(d0.y);
        e1.x = __builtin_amdgcn_exp2f(d1.x); e1.y = __builtin_amdgcn_exp2f(d1.y);
        e2.x = __builtin_amdgcn_exp2f(d2.x); e2.y = __builtin_amdgcn_exp2f(d2.y);
        e3.x = __builtin_amdgcn_exp2f(d3.x); e3.y = __builtin_amdgcn_exp2f(d3.y);
        f2 acc = (e0 + e1) + (e2 + e3);
        s[r] = fmaf(s[r], er, acc.x + acc.y);
        m[r] = mn;
    }
}

// One Sinkhorn half-update, online chunked-max LSE, reg-double-buffered loads.
__launch_bounds__(256, 3)
__global__ void sinkhorn_step(float* __restrict__ ws, float eps, float eps_dec, int half) {
    int bid = blockIdx.x;
    int prob = bid / BPP;                 // 0: xy, 1: xx, 2: yy
    int rem  = bid % BPP;
    int js   = rem & (JSPLIT - 1);
    int rblk = rem / JSPLIT;

    int rc, cc, in_side, out_side;
    if (half == 0) { rc = (prob == 2) ? 1 : 0; cc = (prob == 1) ? 0 : 1; in_side = 1; out_side = 0; }
    else           { rc = (prob == 1) ? 0 : 1; cc = (prob == 2) ? 1 : 0; in_side = 0; out_side = 1; }

    const float k = LOG2E / eps;          // base-2 log scale
    const float nhk = -0.5f * k;
    const int jbase = js * JCHUNK;

    __shared__ float bxL[JCHUNK], byL[JCHUNK], bzL[JCHUNK], uL[JCHUNK];  // 32 KB

    // ---- stage SoA cols + decode input duals into u = k*(g_j - 0.5*|b_j|^2) ----
    {
        const float* cx = ws + PT(cc, 0);
        const float* cy = ws + PT(cc, 1);
        const float* cz = ws + PT(cc, 2);
        const float* cw = ws + PT(cc, 3);
        const float* mp = ws + MPART_OFF + (prob*2 + in_side) * JSPLIT * NPTS;
        const float* sp = ws + SPART_OFF + (prob*2 + in_side) * JSPLIT * NPTS;
        for (int i = threadIdx.x; i < JCHUNK; i += 256) {
            int j = jbase + i;
            float m0 = mp[j], m1 = mp[NPTS + j];
            float s0 = sp[j], s1 = sp[NPTS + j];
            float M = fmaxf(m0, m1);
            float ssum = fmaf(s0, __builtin_amdgcn_exp2f(m0 - M),
                              s1 * __builtin_amdgcn_exp2f(m1 - M));
            float lse2 = M + __builtin_amdgcn_logf(ssum);
            float g = -eps_dec * fmaf(LN2f, lse2, -LOGN);
            bxL[i] = cx[j]; byL[i] = cy[j]; bzL[i] = cz[j];
            uL[i] = fmaf(cw[j], nhk, g * k);
        }
    }
    __syncthreads();

    int wave = threadIdx.x >> 6;
    int lane = threadIdx.x & 63;
    int r0 = rblk * RPB + wave * RPW;

    const float* rx = ws + PT(rc, 0);
    const float* ry = ws + PT(rc, 1);
    const float* rz = ws + PT(rc, 2);
    const float* rw = ws + PT(rc, 3);

    f2 AX[RPW], AY[RPW], AZ[RPW];
    float rak[RPW], m[RPW], s[RPW];
    #pragma unroll
    for (int r = 0; r < RPW; ++r) {
        float ax = rx[r0+r] * k, ay = ry[r0+r] * k, az = rz[r0+r] * k;
        AX[r] = mk2(ax, ax); AY[r] = mk2(ay, ay); AZ[r] = mk2(az, az);
        rak[r] = nhk * rw[r0+r];
        m[r] = -INFINITY; s[r] = 0.0f;
    }

    // ---- main loop: 4 superiters, register double-buffer (prefetch su+1
    //      while computing su); chunk-local max + 1 rescale per 8 elems ----
    {
        f2 BXa[4], BYa[4], BZa[4], Ua[4];
        f2 BXb[4], BYb[4], BZb[4], Ub[4];
        load_su(bxL, byL, bzL, uL, 0 * 512 + lane, BXa, BYa, BZa, Ua);
        load_su(bxL, byL, bzL, uL, 1 * 512 + lane, BXb, BYb, BZb, Ub);
        compute_su(BXa, BYa, BZa, Ua, AX, AY, AZ, m, s);
        load_su(bxL, byL, bzL, uL, 2 * 512 + lane, BXa, BYa, BZa, Ua);
        compute_su(BXb, BYb, BZb, Ub, AX, AY, AZ, m, s);
        load_su(bxL, byL, bzL, uL, 3 * 512 + lane, BXb, BYb, BZb, Ub);
        compute_su(BXa, BYa, BZa, Ua, AX, AY, AZ, m, s);
        compute_su(BXb, BYb, BZb, Ub, AX, AY, AZ, m, s);
    }

    // ---- wave reduce: max butterfly, one rescale, sum butterfly; write partial ----
    float* mout = ws + MPART_OFF + ((prob*2 + out_side) * JSPLIT + js) * NPTS + r0;
    float* sout = ws + SPART_OFF + ((prob*2 + out_side) * JSPLIT + js) * NPTS + r0;
    #pragma unroll
    for (int r = 0; r < RPW; ++r) {
        float M = m[r];
        for (int off = 32; off; off >>= 1) M = fmaxf(M, __shfl_xor(M, off));
        float ss = s[r] * __builtin_amdgcn_exp2f(m[r] - M);
        for (int off = 32; off; off >>= 1) ss += __shfl_xor(ss, off);
        if (lane == 0) { mout[r] = M + rak[r]; sout[r] = ss; }
    }
}

__global__ void finalize_kernel(const float* __restrict__ ws, float* __restrict__ out,
                                float eps) {
    const float* mp = ws + MPART_OFF;
    const float* sp = ws + SPART_OFF;
    int tid = threadIdx.x;
    double acc = 0.0;
    for (int idx = tid; idx < 6 * NPTS; idx += 256) {
        int ps = idx >> 12;            // prob*2+side
        int row = idx & (NPTS - 1);
        int base = ps * JSPLIT * NPTS + row;
        float m0 = mp[base], m1 = mp[base + NPTS];
        float s0 = sp[base], s1 = sp[base + NPTS];
        float M = fmaxf(m0, m1);
        float ssum = fmaf(s0, __builtin_amdgcn_exp2f(m0 - M),
                          s1 * __builtin_amdgcn_exp2f(m1 - M));
        float lse2 = M + __builtin_amdgcn_logf(ssum);
        float dual = -eps * fmaf(LN2f, lse2, -LOGN);
        acc += ((ps < 2) ? 1.0 : -0.5) * (double)dual;
    }
    for (int off = 32; off; off >>= 1) acc += __shfl_xor(acc, off);
    __shared__ double red[4];
    int wave = tid >> 6, lane = tid & 63;
    if (lane == 0) red[wave] = acc;
    __syncthreads();
    if (tid == 0) out[0] = (float)((red[0] + red[1] + red[2] + red[3]) / (double)NPTS);
}

extern "C" void kernel_launch(void* const* d_in, const int* in_sizes, int n_in,
                              void* d_out, int out_size, void* d_ws, size_t ws_size,
                              hipStream_t stream) {
    const float* x = (const float*)d_in[0];
    const float* y = (const float*)d_in[1];
    float* ws = (float*)d_ws;
    float* out = (float*)d_out;

    prep_kernel<<<dim3((NPTS + 255) / 256), dim3(256), 0, stream>>>(x, y, ws);

    float eps_list[NSTEPS];
    for (int st = 0; st < NSTEPS; ++st)
        eps_list[st] = (st < 6) ? ldexpf(4.0f, -2 * st) : 0.0025f;

    for (int st = 0; st < NSTEPS; ++st) {
        float ep = eps_list[st];
        float ed0 = (st == 0) ? ep : eps_list[st - 1];
        sinkhorn_step<<<dim3(3 * BPP), dim3(256), 0, stream>>>(ws, ep, ed0, 0);
        sinkhorn_step<<<dim3(3 * BPP), dim3(256), 0, stream>>>(ws, ep, ep, 1);
    }

    finalize_kernel<<<dim3(1), dim3(256), 0, stream>>>(ws, out, eps_list[NSTEPS - 1]);
}